// Round 1
// baseline (3114.782 us; speedup 1.0000x reference)
//
#include <hip/hip_runtime.h>
#include <hip/hip_bf16.h>
#include <math.h>

#define SEQ 4096
#define DMODEL 1024
#define NHEAD 16
#define DKH 64   // head dim

// ---------------------------------------------------------------------------
// GEMM: C[M][N] = sum_k A[m][k] * B[n][k]   (B row-major N x K, i.e. C = A.B^T)
// Tile 128(M) x 64(N) x 16(K), 256 threads, 8x4 microtile, register prefetch.
// ---------------------------------------------------------------------------
__global__ __launch_bounds__(256)
void gemm_bt(const float* __restrict__ A, const float* __restrict__ B,
             float* __restrict__ C, int M, int N, int K) {
    __shared__ float As[16][128];
    __shared__ float Bs[16][64];

    const int tid = threadIdx.x;
    const int tx = tid & 15;   // col group (0..15) -> 4 cols each
    const int ty = tid >> 4;   // row group (0..15) -> 8 rows each
    const int m0 = blockIdx.y * 128;
    const int n0 = blockIdx.x * 64;

    // loader mapping: each thread loads 2 float4 of A, 1 float4 of B per k-step
    const int lr  = tid >> 2;  // 0..63
    const int lc4 = tid & 3;   // 0..3  -> k-cols lc4*4..lc4*4+3
    const float* Ap0 = A + (size_t)(m0 + lr) * K + lc4 * 4;
    const float* Ap1 = Ap0 + (size_t)64 * K;
    const float* Bp  = B + (size_t)(n0 + lr) * K + lc4 * 4;

    float acc[8][4];
#pragma unroll
    for (int i = 0; i < 8; i++)
#pragma unroll
        for (int j = 0; j < 4; j++) acc[i][j] = 0.f;

    float4 a0 = *(const float4*)(Ap0);
    float4 a1 = *(const float4*)(Ap1);
    float4 b0 = *(const float4*)(Bp);

    for (int k0 = 0; k0 < K; k0 += 16) {
        __syncthreads();
        // store current k-slab to LDS (transposed: As[kk][row])
        As[lc4 * 4 + 0][lr] = a0.x;  As[lc4 * 4 + 1][lr] = a0.y;
        As[lc4 * 4 + 2][lr] = a0.z;  As[lc4 * 4 + 3][lr] = a0.w;
        As[lc4 * 4 + 0][64 + lr] = a1.x;  As[lc4 * 4 + 1][64 + lr] = a1.y;
        As[lc4 * 4 + 2][64 + lr] = a1.z;  As[lc4 * 4 + 3][64 + lr] = a1.w;
        Bs[lc4 * 4 + 0][lr] = b0.x;  Bs[lc4 * 4 + 1][lr] = b0.y;
        Bs[lc4 * 4 + 2][lr] = b0.z;  Bs[lc4 * 4 + 3][lr] = b0.w;
        __syncthreads();

        // prefetch next slab while computing this one
        if (k0 + 16 < K) {
            a0 = *(const float4*)(Ap0 + k0 + 16);
            a1 = *(const float4*)(Ap1 + k0 + 16);
            b0 = *(const float4*)(Bp  + k0 + 16);
        }

#pragma unroll
        for (int kk = 0; kk < 16; kk++) {
            float4 av0 = *(const float4*)&As[kk][ty * 8];
            float4 av1 = *(const float4*)&As[kk][ty * 8 + 4];
            float4 bv0 = *(const float4*)&Bs[kk][tx * 4];
            float a_[8] = {av0.x, av0.y, av0.z, av0.w, av1.x, av1.y, av1.z, av1.w};
            float b_[4] = {bv0.x, bv0.y, bv0.z, bv0.w};
#pragma unroll
            for (int i = 0; i < 8; i++)
#pragma unroll
                for (int j = 0; j < 4; j++) acc[i][j] += a_[i] * b_[j];
        }
    }

#pragma unroll
    for (int i = 0; i < 8; i++) {
        float4 o4 = make_float4(acc[i][0], acc[i][1], acc[i][2], acc[i][3]);
        *(float4*)(C + (size_t)(m0 + ty * 8 + i) * N + n0 + tx * 4) = o4;
    }
}

// ---------------------------------------------------------------------------
// RoPE applied in-place to q and k. Interleaved pairs (2i, 2i+1) per head.
// freq_i = 10000^(-i/32), angle = pos * freq_i.
// ---------------------------------------------------------------------------
__global__ __launch_bounds__(256)
void rope_kernel(float* __restrict__ q, float* __restrict__ k) {
    int idx = blockIdx.x * 256 + threadIdx.x;      // over SEQ * 512 pairs
    if (idx >= SEQ * (DMODEL / 2)) return;
    int s  = idx >> 9;         // / 512
    int j  = idx & 511;
    int hh = j >> 5;           // head
    int i  = j & 31;           // pair index within head
    const float LOG1E4_OVER32 = 0.28782313662425572f;   // ln(10000)/32
    float freq = __expf(-(float)i * LOG1E4_OVER32);
    float ang  = (float)s * freq;
    float c, sn;
    __sincosf(ang, &sn, &c);
    size_t base = (size_t)s * DMODEL + hh * DKH + 2 * i;
    float e = q[base], o_ = q[base + 1];
    q[base]     = e * c - o_ * sn;
    q[base + 1] = e * sn + o_ * c;
    e = k[base]; o_ = k[base + 1];
    k[base]     = e * c - o_ * sn;
    k[base + 1] = e * sn + o_ * c;
}

// ---------------------------------------------------------------------------
// Causal flash attention, fp32.
// Block = 256 threads = 4 waves; block handles 64 queries of one head
// (thread lane = one query row). Wave w processes key tiles kt ≡ w (mod 4)
// (32 keys per tile) with its own private LDS K/V tile (no barriers in the
// main loop — trip counts differ per wave). Partials merged through LDS.
// ---------------------------------------------------------------------------
__global__ __launch_bounds__(256)
void attn_fwd(const float* __restrict__ Q, const float* __restrict__ K,
              const float* __restrict__ V, float* __restrict__ O) {
    __shared__ float smem[4 * 2 * 32 * 64];   // 4 waves x (K tile + V tile) = 64 KiB

    const int tid  = threadIdx.x;
    const int w    = tid >> 6;
    const int lane = tid & 63;
    const int h     = blockIdx.y;
    const int qbase = blockIdx.x * 64;
    const int qrow  = qbase + lane;

    float* Ks = smem + w * 4096;
    float* Vs = Ks + 2048;

    // load q row (scaled by 1/sqrt(64))
    float4 qv[16];
    const float* qp = Q + (size_t)qrow * DMODEL + h * DKH;
#pragma unroll
    for (int i = 0; i < 16; i++) {
        float4 t = *(const float4*)(qp + i * 4);
        qv[i] = make_float4(t.x * 0.125f, t.y * 0.125f, t.z * 0.125f, t.w * 0.125f);
    }
    float4 acc[16];
#pragma unroll
    for (int i = 0; i < 16; i++) acc[i] = make_float4(0.f, 0.f, 0.f, 0.f);
    float m = -INFINITY, l = 0.f;

    const int ktmax = (qbase + 63) >> 5;   // inclusive
    for (int kt = w; kt <= ktmax; kt += 4) {
        const int kbase = kt * 32;
        const float* kp = K + (size_t)kbase * DMODEL + h * DKH;
        const float* vp = V + (size_t)kbase * DMODEL + h * DKH;
        // stage 32x64 K and V tiles (wave-private, no barrier needed)
#pragma unroll
        for (int r = 0; r < 8; r++) {
            int f = r * 64 + lane;
            int row = f >> 4, c4 = f & 15;
            *(float4*)(Ks + row * 64 + c4 * 4) =
                *(const float4*)(kp + (size_t)row * DMODEL + c4 * 4);
            *(float4*)(Vs + row * 64 + c4 * 4) =
                *(const float4*)(vp + (size_t)row * DMODEL + c4 * 4);
        }

        float s_[32];
#pragma unroll
        for (int kk = 0; kk < 32; kk++) {
            float4 sum = make_float4(0.f, 0.f, 0.f, 0.f);
#pragma unroll
            for (int d = 0; d < 16; d++) {
                float4 kv = *(const float4*)(Ks + kk * 64 + d * 4);
                sum.x += qv[d].x * kv.x;  sum.y += qv[d].y * kv.y;
                sum.z += qv[d].z * kv.z;  sum.w += qv[d].w * kv.w;
            }
            float sv = (sum.x + sum.y) + (sum.z + sum.w);
            s_[kk] = (kbase + kk <= qrow) ? sv : -INFINITY;
        }
        float tmax = s_[0];
#pragma unroll
        for (int kk = 1; kk < 32; kk++) tmax = fmaxf(tmax, s_[kk]);
        float mnew = fmaxf(m, tmax);
        if (mnew > -INFINITY) {   // skip fully-masked tiles (keeps exp args finite)
            float alpha = expf(m - mnew);
            l *= alpha;
#pragma unroll
            for (int i = 0; i < 16; i++) {
                acc[i].x *= alpha; acc[i].y *= alpha;
                acc[i].z *= alpha; acc[i].w *= alpha;
            }
#pragma unroll
            for (int kk = 0; kk < 32; kk++) {
                float p = expf(s_[kk] - mnew);
                l += p;
#pragma unroll
                for (int d = 0; d < 16; d++) {
                    float4 vv = *(const float4*)(Vs + kk * 64 + d * 4);
                    acc[d].x += p * vv.x;  acc[d].y += p * vv.y;
                    acc[d].z += p * vv.z;  acc[d].w += p * vv.w;
                }
            }
            m = mnew;
        }
    }

    // ---- merge the 4 waves' partial (m, l, acc) ----
    __syncthreads();
    float* red_m = smem;          // [4][64]
    float* red_l = smem + 256;    // [4][64]
    float* buf   = smem + 512;    // [4][64][16]
    red_m[w * 64 + lane] = m;
    red_l[w * 64 + lane] = l;
    __syncthreads();

    float sc0 = 0.f, sc1 = 0.f, sc2 = 0.f, sc3 = 0.f;
    if (w == 0) {
        float m0_ = red_m[lane],       m1_ = red_m[64 + lane];
        float m2_ = red_m[128 + lane], m3_ = red_m[192 + lane];
        float ms = fmaxf(fmaxf(m0_, m1_), fmaxf(m2_, m3_));
        float e0 = expf(m0_ - ms), e1 = expf(m1_ - ms);
        float e2 = expf(m2_ - ms), e3 = expf(m3_ - ms);
        float ls = red_l[lane] * e0 + red_l[64 + lane] * e1 +
                   red_l[128 + lane] * e2 + red_l[192 + lane] * e3;
        float invl = 1.f / ls;
        sc0 = e0 * invl; sc1 = e1 * invl; sc2 = e2 * invl; sc3 = e3 * invl;
    }

    float* op = O + (size_t)qrow * DMODEL + h * DKH;
#pragma unroll
    for (int c = 0; c < 4; c++) {      // 16 dims per chunk
        __syncthreads();
#pragma unroll
        for (int d4 = 0; d4 < 4; d4++) {
            *(float4*)(buf + w * 1024 + lane * 16 + d4 * 4) = acc[c * 4 + d4];
        }
        __syncthreads();
        if (w == 0) {
#pragma unroll
            for (int d4 = 0; d4 < 4; d4++) {
                float4 r0 = *(float4*)(buf + lane * 16 + d4 * 4);
                float4 r1 = *(float4*)(buf + 1024 + lane * 16 + d4 * 4);
                float4 r2 = *(float4*)(buf + 2048 + lane * 16 + d4 * 4);
                float4 r3 = *(float4*)(buf + 3072 + lane * 16 + d4 * 4);
                float4 o4;
                o4.x = r0.x * sc0 + r1.x * sc1 + r2.x * sc2 + r3.x * sc3;
                o4.y = r0.y * sc0 + r1.y * sc1 + r2.y * sc2 + r3.y * sc3;
                o4.z = r0.z * sc0 + r1.z * sc1 + r2.z * sc2 + r3.z * sc3;
                o4.w = r0.w * sc0 + r1.w * sc1 + r2.w * sc2 + r3.w * sc3;
                *(float4*)(op + c * 16 + d4 * 4) = o4;
            }
        }
    }
}

// ---------------------------------------------------------------------------
extern "C" void kernel_launch(void* const* d_in, const int* in_sizes, int n_in,
                              void* d_out, int out_size, void* d_ws, size_t ws_size,
                              hipStream_t stream) {
    const float* x  = (const float*)d_in[0];
    const float* Wq = (const float*)d_in[1];
    const float* Wk = (const float*)d_in[2];
    const float* Wv = (const float*)d_in[3];
    const float* Wo = (const float*)d_in[4];
    float* out = (float*)d_out;

    float* q = (float*)d_ws;
    float* k = q + (size_t)SEQ * DMODEL;
    float* v = k + (size_t)SEQ * DMODEL;
    float* o = v + (size_t)SEQ * DMODEL;

    dim3 gemm_grid(DMODEL / 64, SEQ / 128);   // (16, 32)
    gemm_bt<<<gemm_grid, 256, 0, stream>>>(x, Wq, q, SEQ, DMODEL, DMODEL);
    gemm_bt<<<gemm_grid, 256, 0, stream>>>(x, Wk, k, SEQ, DMODEL, DMODEL);
    gemm_bt<<<gemm_grid, 256, 0, stream>>>(x, Wv, v, SEQ, DMODEL, DMODEL);

    rope_kernel<<<(SEQ * (DMODEL / 2) + 255) / 256, 256, 0, stream>>>(q, k);

    attn_fwd<<<dim3(SEQ / 64, NHEAD), 256, 0, stream>>>(q, k, v, o);

    gemm_bt<<<gemm_grid, 256, 0, stream>>>(o, Wo, out, SEQ, DMODEL, DMODEL);
}

// Round 8
// 489.851 us; speedup vs baseline: 6.3586x; 6.3586x over previous
//
#include <hip/hip_runtime.h>
#include <math.h>

#define SEQ 4096
#define DMODEL 1024
#define NHEAD 16
#define DKH 64   // head dim

typedef __attribute__((ext_vector_type(8))) short bf16x8;
typedef __attribute__((ext_vector_type(4))) float f32x4;

// fp32 -> bf16 bits, round-to-nearest-even
__device__ __forceinline__ ushort f2b(float x) {
    unsigned u = __float_as_uint(x);
    return (ushort)((u + 0x7fffu + ((u >> 16) & 1u)) >> 16);
}
// bf16 bits -> fp32
__device__ __forceinline__ float b2f(ushort u) {
    return __uint_as_float(((unsigned)u) << 16);
}

// ---------------------------------------------------------------------------
// Convert x (4096x1024) and the four 1024x1024 weights to bf16, one launch.
// Blocks [0,4096) -> x ; then 1024 blocks per weight. 4 elems/thread.
// ---------------------------------------------------------------------------
__global__ __launch_bounds__(256)
void conv_bf16(const float* __restrict__ x,  const float* __restrict__ wq,
               const float* __restrict__ wk, const float* __restrict__ wv,
               const float* __restrict__ wo,
               ushort* __restrict__ xb,  ushort* __restrict__ wqb,
               ushort* __restrict__ wkb, ushort* __restrict__ wvb,
               ushort* __restrict__ wob) {
    const int b = blockIdx.x;
    const float* src; ushort* dst; int idx;
    if (b < 4096) {
        src = x; dst = xb; idx = b * 256 + threadIdx.x;
    } else {
        int t = b - 4096;
        int which = t >> 10;            // 0..3
        idx = (t & 1023) * 256 + threadIdx.x;
        if      (which == 0) { src = wq; dst = wqb; }
        else if (which == 1) { src = wk; dst = wkb; }
        else if (which == 2) { src = wv; dst = wvb; }
        else                 { src = wo; dst = wob; }
    }
    float4 f = ((const float4*)src)[idx];
    ushort4 o;
    o.x = f2b(f.x); o.y = f2b(f.y); o.z = f2b(f.z); o.w = f2b(f.w);
    ((ushort4*)dst)[idx] = o;
}

// ---------------------------------------------------------------------------
// bf16 MFMA GEMM: C[M][N] = sum_k A[m][k] * B[n][k]  (C = A.B^T), fp32 acc.
// Tile 128x128, BK=32, 256 threads = 4 waves (2x2), each wave 64x64 out
// (4x4 fragments of 16x16x32). Reg-staged LDS, stride 40 ushort (80 B:
// 16B-aligned, 2-way bank aliasing only). OUT_BF16 selects bf16/fp32 C.
// Fragment layouts (m89/m92-verified):
//   A/B in : lane holds 8 contiguous k at row/col = lane&15, k0 = (lane>>4)*8
//   C/D out: col = lane&15, row = (lane>>4)*4 + reg
// ---------------------------------------------------------------------------
#define GSTR 40

template<bool OUT_BF16>
__global__ __launch_bounds__(256)
void gemm_bf16(const ushort* __restrict__ A, const ushort* __restrict__ B,
               void* __restrict__ Cv, int M, int N, int K) {
    __shared__ __attribute__((aligned(16))) ushort As[128 * GSTR];
    __shared__ __attribute__((aligned(16))) ushort Bs[128 * GSTR];

    const int tid  = threadIdx.x;
    const int lane = tid & 63;
    const int w    = tid >> 6;
    const int wr   = w >> 1, wc = w & 1;
    const int lrow = lane & 15, lgrp = lane >> 4;
    const int m0 = blockIdx.y * 128;
    const int n0 = blockIdx.x * 128;

    // staging: 512 chunks of 8 bf16 per operand; thread does chunks tid, tid+256
    const int srow = tid >> 2;            // 0..63
    const int skc  = (tid & 3) * 8;       // 0,8,16,24
    const ushort* Ap0 = A + (size_t)(m0 + srow) * K + skc;
    const ushort* Ap1 = Ap0 + (size_t)64 * K;
    const ushort* Bp0 = B + (size_t)(n0 + srow) * K + skc;
    const ushort* Bp1 = Bp0 + (size_t)64 * K;
    ushort* sA0 = &As[srow * GSTR + skc];
    ushort* sA1 = &As[(srow + 64) * GSTR + skc];
    ushort* sB0 = &Bs[srow * GSTR + skc];
    ushort* sB1 = &Bs[(srow + 64) * GSTR + skc];

    f32x4 acc[4][4];
#pragma unroll
    for (int i = 0; i < 4; i++)
#pragma unroll
        for (int j = 0; j < 4; j++) acc[i][j] = (f32x4){0.f, 0.f, 0.f, 0.f};

    bf16x8 ra0 = *(const bf16x8*)(Ap0);
    bf16x8 ra1 = *(const bf16x8*)(Ap1);
    bf16x8 rb0 = *(const bf16x8*)(Bp0);
    bf16x8 rb1 = *(const bf16x8*)(Bp1);

    const int NT = K >> 5;   // BK=32
    for (int kt = 0; kt < NT; kt++) {
        __syncthreads();
        *(bf16x8*)sA0 = ra0;  *(bf16x8*)sA1 = ra1;
        *(bf16x8*)sB0 = rb0;  *(bf16x8*)sB1 = rb1;
        __syncthreads();

        if (kt + 1 < NT) {
            const int ko = (kt + 1) * 32;
            ra0 = *(const bf16x8*)(Ap0 + ko);
            ra1 = *(const bf16x8*)(Ap1 + ko);
            rb0 = *(const bf16x8*)(Bp0 + ko);
            rb1 = *(const bf16x8*)(Bp1 + ko);
        }

        bf16x8 af[4], bfr[4];
#pragma unroll
        for (int i = 0; i < 4; i++)
            af[i] = *(const bf16x8*)&As[(wr * 64 + i * 16 + lrow) * GSTR + lgrp * 8];
#pragma unroll
        for (int j = 0; j < 4; j++)
            bfr[j] = *(const bf16x8*)&Bs[(wc * 64 + j * 16 + lrow) * GSTR + lgrp * 8];
#pragma unroll
        for (int i = 0; i < 4; i++)
#pragma unroll
            for (int j = 0; j < 4; j++)
                acc[i][j] = __builtin_amdgcn_mfma_f32_16x16x32_bf16(af[i], bfr[j], acc[i][j], 0, 0, 0);
    }

    // epilogue: C/D layout col=lane&15, row=lgrp*4+reg
#pragma unroll
    for (int i = 0; i < 4; i++) {
#pragma unroll
        for (int j = 0; j < 4; j++) {
#pragma unroll
            for (int r = 0; r < 4; r++) {
                const size_t row = m0 + wr * 64 + i * 16 + lgrp * 4 + r;
                const size_t col = n0 + wc * 64 + j * 16 + lrow;
                if constexpr (OUT_BF16)
                    ((ushort*)Cv)[row * N + col] = f2b(acc[i][j][r]);
                else
                    ((float*)Cv)[row * N + col] = acc[i][j][r];
            }
        }
    }
}

// ---------------------------------------------------------------------------
// RoPE in-place on bf16 q and k (interleaved pairs per head).
// ---------------------------------------------------------------------------
__global__ __launch_bounds__(256)
void rope_bf16(ushort* __restrict__ q, ushort* __restrict__ k) {
    int idx = blockIdx.x * 256 + threadIdx.x;      // over SEQ * 512 pairs
    if (idx >= SEQ * (DMODEL / 2)) return;
    int s  = idx >> 9;
    int j  = idx & 511;
    int hh = j >> 5;
    int i  = j & 31;
    const float LOG1E4_OVER32 = 0.28782313662425572f;   // ln(10000)/32
    float freq = __expf(-(float)i * LOG1E4_OVER32);
    float ang  = (float)s * freq;
    float c, sn;
    __sincosf(ang, &sn, &c);
    size_t base = (size_t)s * DMODEL + hh * DKH + 2 * i;
    float e = b2f(q[base]), o_ = b2f(q[base + 1]);
    q[base]     = f2b(e * c - o_ * sn);
    q[base + 1] = f2b(e * sn + o_ * c);
    e = b2f(k[base]); o_ = b2f(k[base + 1]);
    k[base]     = f2b(e * c - o_ * sn);
    k[base + 1] = f2b(e * sn + o_ * c);
}

// ---------------------------------------------------------------------------
// Causal flash attention, bf16 in/out, MFMA 16x16x32, fp32 accumulate.
// Block = 256 threads = 4 waves, 64 queries of one head (wave w: rows w*16..).
// 1/sqrt(64) applied to S post-MFMA (exact). LSTR=72 keeps 16B alignment and
// breaks power-of-2 bank stride.
// ---------------------------------------------------------------------------
#define LSTR 72

__global__ __launch_bounds__(256)
void attn_mfma(const ushort* __restrict__ Q, const ushort* __restrict__ K,
               const ushort* __restrict__ V, ushort* __restrict__ O) {
    __shared__ __attribute__((aligned(16))) ushort Ks[64 * LSTR];
    __shared__ __attribute__((aligned(16))) ushort Vs[64 * LSTR];   // [d][key]
    __shared__ __attribute__((aligned(16))) ushort Ps[4][16 * LSTR];

    const int tid  = threadIdx.x;
    const int w    = tid >> 6;
    const int lane = tid & 63;
    const int lrow = lane & 15;
    const int lgrp = lane >> 4;
    const int h     = blockIdx.y;
    const int qbase = blockIdx.x * 64;

    // ---- Q fragments: direct bf16 16B loads ----
    const int qr = qbase + w * 16 + lrow;
    const ushort* qp = Q + (size_t)qr * DMODEL + h * DKH + lgrp * 8;
    bf16x8 qfrag[2];
    qfrag[0] = *(const bf16x8*)(qp);
    qfrag[1] = *(const bf16x8*)(qp + 32);

    f32x4 o_acc[4];
#pragma unroll
    for (int t = 0; t < 4; t++) o_acc[t] = (f32x4){0.f, 0.f, 0.f, 0.f};
    float m_r[4], l_r[4];
#pragma unroll
    for (int r = 0; r < 4; r++) { m_r[r] = -INFINITY; l_r[r] = 0.f; }

    for (int kt = 0; kt <= (int)blockIdx.x; kt++) {
        const int kbase = kt * 64;
        __syncthreads();   // previous tile's compute done before overwrite
        // ---- stage K (row-major) and V (transposed) ----
        {
            const ushort* Kp = K + (size_t)kbase * DMODEL + h * DKH;
            const ushort* Vp = V + (size_t)kbase * DMODEL + h * DKH;
#pragma unroll
            for (int cc = 0; cc < 2; cc++) {
                const int c   = tid + cc * 256;     // chunk 0..511
                const int row = c >> 3;             // key in tile
                const int col = (c & 7) * 8;        // d offset
                *(bf16x8*)&Ks[row * LSTR + col] =
                    *(const bf16x8*)(Kp + (size_t)row * DMODEL + col);
                bf16x8 vv = *(const bf16x8*)(Vp + (size_t)row * DMODEL + col);
#pragma unroll
                for (int jj = 0; jj < 8; jj++)
                    Vs[(col + jj) * LSTR + row] = (ushort)vv[jj];
            }
        }
        __syncthreads();

        // ---- QK^T: S[16 q][64 keys] per wave ----
        f32x4 s[4];
#pragma unroll
        for (int n = 0; n < 4; n++) {
            f32x4 acc = (f32x4){0.f, 0.f, 0.f, 0.f};
#pragma unroll
            for (int ks = 0; ks < 2; ks++) {
                bf16x8 kf = *(const bf16x8*)&Ks[(n * 16 + lrow) * LSTR + lgrp * 8 + ks * 32];
                acc = __builtin_amdgcn_mfma_f32_16x16x32_bf16(qfrag[ks], kf, acc, 0, 0, 0);
            }
            s[n] = acc;
        }

        // ---- scale by 1/sqrt(64) + causal mask ----
        const int myq = qbase + w * 16 + lgrp * 4;
#pragma unroll
        for (int n = 0; n < 4; n++) {
            const int key = kbase + n * 16 + lrow;
#pragma unroll
            for (int r = 0; r < 4; r++)
                s[n][r] = (key > myq + r) ? -INFINITY : s[n][r] * 0.125f;
        }

        // ---- online softmax (row = query), wave-parallel over 16-lane groups ----
        float tmax[4];
#pragma unroll
        for (int r = 0; r < 4; r++)
            tmax[r] = fmaxf(fmaxf(s[0][r], s[1][r]), fmaxf(s[2][r], s[3][r]));
#pragma unroll
        for (int off = 1; off < 16; off <<= 1) {
#pragma unroll
            for (int r = 0; r < 4; r++)
                tmax[r] = fmaxf(tmax[r], __shfl_xor(tmax[r], off));
        }
        float alpha[4];
#pragma unroll
        for (int r = 0; r < 4; r++) {
            float mnew = fmaxf(m_r[r], tmax[r]);
            alpha[r] = __expf(m_r[r] - mnew);   // exp(-inf)=0 on first tile
            m_r[r] = mnew;
        }
#pragma unroll
        for (int t = 0; t < 4; t++)
#pragma unroll
            for (int r = 0; r < 4; r++) o_acc[t][r] *= alpha[r];

        float psum[4] = {0.f, 0.f, 0.f, 0.f};
#pragma unroll
        for (int n = 0; n < 4; n++) {
#pragma unroll
            for (int r = 0; r < 4; r++) {
                float p = __expf(s[n][r] - m_r[r]);   // masked: exp(-inf)=0
                psum[r] += p;
                Ps[w][(lgrp * 4 + r) * LSTR + n * 16 + lrow] = f2b(p);
            }
        }
#pragma unroll
        for (int off = 1; off < 16; off <<= 1) {
#pragma unroll
            for (int r = 0; r < 4; r++) psum[r] += __shfl_xor(psum[r], off);
        }
#pragma unroll
        for (int r = 0; r < 4; r++) l_r[r] = l_r[r] * alpha[r] + psum[r];

        // ---- PV: O += P * V   (P from wave-private LDS, V transposed) ----
#pragma unroll
        for (int ks = 0; ks < 2; ks++) {
            bf16x8 pa = *(const bf16x8*)&Ps[w][lrow * LSTR + lgrp * 8 + ks * 32];
#pragma unroll
            for (int t = 0; t < 4; t++) {
                bf16x8 vb = *(const bf16x8*)&Vs[(t * 16 + lrow) * LSTR + lgrp * 8 + ks * 32];
                o_acc[t] = __builtin_amdgcn_mfma_f32_16x16x32_bf16(pa, vb, o_acc[t], 0, 0, 0);
            }
        }
    }

    // ---- epilogue: normalize and store bf16 ----
    float invl[4];
#pragma unroll
    for (int r = 0; r < 4; r++) invl[r] = 1.0f / l_r[r];
    ushort* op = O + (size_t)(qbase + w * 16) * DMODEL + h * DKH;
#pragma unroll
    for (int t = 0; t < 4; t++)
#pragma unroll
        for (int r = 0; r < 4; r++)
            op[(size_t)(lgrp * 4 + r) * DMODEL + t * 16 + lrow] = f2b(o_acc[t][r] * invl[r]);
}

// ---------------------------------------------------------------------------
extern "C" void kernel_launch(void* const* d_in, const int* in_sizes, int n_in,
                              void* d_out, int out_size, void* d_ws, size_t ws_size,
                              hipStream_t stream) {
    const float* x  = (const float*)d_in[0];
    const float* Wq = (const float*)d_in[1];
    const float* Wk = (const float*)d_in[2];
    const float* Wv = (const float*)d_in[3];
    const float* Wo = (const float*)d_in[4];
    float* out = (float*)d_out;

    const size_t NM = (size_t)SEQ * DMODEL;      // 4 M elems
    const size_t NW = (size_t)DMODEL * DMODEL;   // 1 M elems
    ushort* qb  = (ushort*)d_ws;
    ushort* kb  = qb + NM;
    ushort* vb  = kb + NM;
    ushort* ob  = vb + NM;
    ushort* xb  = ob + NM;
    ushort* wqb = xb + NM;
    ushort* wkb = wqb + NW;
    ushort* wvb = wkb + NW;
    ushort* wob = wvb + NW;   // total 48 MB

    conv_bf16<<<8192, 256, 0, stream>>>(x, Wq, Wk, Wv, Wo, xb, wqb, wkb, wvb, wob);

    dim3 ggrid(DMODEL / 128, SEQ / 128);   // (8, 32)
    gemm_bf16<true><<<ggrid, 256, 0, stream>>>(xb, wqb, qb, SEQ, DMODEL, DMODEL);
    gemm_bf16<true><<<ggrid, 256, 0, stream>>>(xb, wkb, kb, SEQ, DMODEL, DMODEL);
    gemm_bf16<true><<<ggrid, 256, 0, stream>>>(xb, wvb, vb, SEQ, DMODEL, DMODEL);

    rope_bf16<<<SEQ * (DMODEL / 2) / 256, 256, 0, stream>>>(qb, kb);

    attn_mfma<<<dim3(SEQ / 64, NHEAD), 256, 0, stream>>>(qb, kb, vb, ob);

    gemm_bf16<false><<<ggrid, 256, 0, stream>>>(ob, wob, out, SEQ, DMODEL, DMODEL);
}

// Round 10
// 367.418 us; speedup vs baseline: 8.4775x; 1.3332x over previous
//
#include <hip/hip_runtime.h>
#include <math.h>

#define SEQ 4096
#define DMODEL 1024
#define NHEAD 16
#define DKH 64   // head dim

typedef __attribute__((ext_vector_type(8))) short bf16x8;
typedef __attribute__((ext_vector_type(4))) float f32x4;

// fp32 -> bf16 bits, round-to-nearest-even
__device__ __forceinline__ ushort f2b(float x) {
    unsigned u = __float_as_uint(x);
    return (ushort)((u + 0x7fffu + ((u >> 16) & 1u)) >> 16);
}
// bf16 bits -> fp32
__device__ __forceinline__ float b2f(ushort u) {
    return __uint_as_float(((unsigned)u) << 16);
}

// DPP row_ror:n combine (row = 16 lanes on CDNA). VALU-speed, replaces DS shfl.
#define DPP_ROR_F(x, ctrl) \
    __int_as_float(__builtin_amdgcn_update_dpp(__float_as_int(x), __float_as_int(x), (ctrl), 0xf, 0xf, false))

__device__ __forceinline__ float rowmax16(float x) {
    x = fmaxf(x, DPP_ROR_F(x, 0x121));   // ror 1
    x = fmaxf(x, DPP_ROR_F(x, 0x122));   // ror 2
    x = fmaxf(x, DPP_ROR_F(x, 0x124));   // ror 4
    x = fmaxf(x, DPP_ROR_F(x, 0x128));   // ror 8
    return x;
}
__device__ __forceinline__ float rowsum16(float x) {
    x += DPP_ROR_F(x, 0x121);
    x += DPP_ROR_F(x, 0x122);
    x += DPP_ROR_F(x, 0x124);
    x += DPP_ROR_F(x, 0x128);
    return x;
}

// ---------------------------------------------------------------------------
// Convert x (4096x1024) and the four 1024x1024 weights to bf16, one launch.
// ---------------------------------------------------------------------------
__global__ __launch_bounds__(256)
void conv_bf16(const float* __restrict__ x,  const float* __restrict__ wq,
               const float* __restrict__ wk, const float* __restrict__ wv,
               const float* __restrict__ wo,
               ushort* __restrict__ xb,  ushort* __restrict__ wqb,
               ushort* __restrict__ wkb, ushort* __restrict__ wvb,
               ushort* __restrict__ wob) {
    const int b = blockIdx.x;
    const float* src; ushort* dst; int idx;
    if (b < 4096) {
        src = x; dst = xb; idx = b * 256 + threadIdx.x;
    } else {
        int t = b - 4096;
        int which = t >> 10;            // 0..3
        idx = (t & 1023) * 256 + threadIdx.x;
        if      (which == 0) { src = wq; dst = wqb; }
        else if (which == 1) { src = wk; dst = wkb; }
        else if (which == 2) { src = wv; dst = wvb; }
        else                 { src = wo; dst = wob; }
    }
    float4 f = ((const float4*)src)[idx];
    ushort4 o;
    o.x = f2b(f.x); o.y = f2b(f.y); o.z = f2b(f.z); o.w = f2b(f.w);
    ((ushort4*)dst)[idx] = o;
}

// ---------------------------------------------------------------------------
// bf16 MFMA GEMM: C[M][N] = sum_k A[m][k] * B[n][k]  (C = A.B^T), fp32 acc.
// Tile 128x128, BK=32, 256 threads = 4 waves (2x2), each wave 64x64 out.
// (unchanged from round-8 passing version)
// ---------------------------------------------------------------------------
#define GSTR 40

template<bool OUT_BF16>
__global__ __launch_bounds__(256)
void gemm_bf16(const ushort* __restrict__ A, const ushort* __restrict__ B,
               void* __restrict__ Cv, int M, int N, int K) {
    __shared__ __attribute__((aligned(16))) ushort As[128 * GSTR];
    __shared__ __attribute__((aligned(16))) ushort Bs[128 * GSTR];

    const int tid  = threadIdx.x;
    const int lane = tid & 63;
    const int w    = tid >> 6;
    const int wr   = w >> 1, wc = w & 1;
    const int lrow = lane & 15, lgrp = lane >> 4;
    const int m0 = blockIdx.y * 128;
    const int n0 = blockIdx.x * 128;

    const int srow = tid >> 2;            // 0..63
    const int skc  = (tid & 3) * 8;       // 0,8,16,24
    const ushort* Ap0 = A + (size_t)(m0 + srow) * K + skc;
    const ushort* Ap1 = Ap0 + (size_t)64 * K;
    const ushort* Bp0 = B + (size_t)(n0 + srow) * K + skc;
    const ushort* Bp1 = Bp0 + (size_t)64 * K;
    ushort* sA0 = &As[srow * GSTR + skc];
    ushort* sA1 = &As[(srow + 64) * GSTR + skc];
    ushort* sB0 = &Bs[srow * GSTR + skc];
    ushort* sB1 = &Bs[(srow + 64) * GSTR + skc];

    f32x4 acc[4][4];
#pragma unroll
    for (int i = 0; i < 4; i++)
#pragma unroll
        for (int j = 0; j < 4; j++) acc[i][j] = (f32x4){0.f, 0.f, 0.f, 0.f};

    bf16x8 ra0 = *(const bf16x8*)(Ap0);
    bf16x8 ra1 = *(const bf16x8*)(Ap1);
    bf16x8 rb0 = *(const bf16x8*)(Bp0);
    bf16x8 rb1 = *(const bf16x8*)(Bp1);

    const int NT = K >> 5;   // BK=32
    for (int kt = 0; kt < NT; kt++) {
        __syncthreads();
        *(bf16x8*)sA0 = ra0;  *(bf16x8*)sA1 = ra1;
        *(bf16x8*)sB0 = rb0;  *(bf16x8*)sB1 = rb1;
        __syncthreads();

        if (kt + 1 < NT) {
            const int ko = (kt + 1) * 32;
            ra0 = *(const bf16x8*)(Ap0 + ko);
            ra1 = *(const bf16x8*)(Ap1 + ko);
            rb0 = *(const bf16x8*)(Bp0 + ko);
            rb1 = *(const bf16x8*)(Bp1 + ko);
        }

        bf16x8 af[4], bfr[4];
#pragma unroll
        for (int i = 0; i < 4; i++)
            af[i] = *(const bf16x8*)&As[(wr * 64 + i * 16 + lrow) * GSTR + lgrp * 8];
#pragma unroll
        for (int j = 0; j < 4; j++)
            bfr[j] = *(const bf16x8*)&Bs[(wc * 64 + j * 16 + lrow) * GSTR + lgrp * 8];
#pragma unroll
        for (int i = 0; i < 4; i++)
#pragma unroll
            for (int j = 0; j < 4; j++)
                acc[i][j] = __builtin_amdgcn_mfma_f32_16x16x32_bf16(af[i], bfr[j], acc[i][j], 0, 0, 0);
    }

#pragma unroll
    for (int i = 0; i < 4; i++) {
#pragma unroll
        for (int j = 0; j < 4; j++) {
#pragma unroll
            for (int r = 0; r < 4; r++) {
                const size_t row = m0 + wr * 64 + i * 16 + lgrp * 4 + r;
                const size_t col = n0 + wc * 64 + j * 16 + lrow;
                if constexpr (OUT_BF16)
                    ((ushort*)Cv)[row * N + col] = f2b(acc[i][j][r]);
                else
                    ((float*)Cv)[row * N + col] = acc[i][j][r];
            }
        }
    }
}

// ---------------------------------------------------------------------------
// RoPE in-place on bf16 q and k (interleaved pairs per head).
// ---------------------------------------------------------------------------
__global__ __launch_bounds__(256)
void rope_bf16(ushort* __restrict__ q, ushort* __restrict__ k) {
    int idx = blockIdx.x * 256 + threadIdx.x;      // over SEQ * 512 pairs
    if (idx >= SEQ * (DMODEL / 2)) return;
    int s  = idx >> 9;
    int j  = idx & 511;
    int hh = j >> 5;
    int i  = j & 31;
    const float LOG1E4_OVER32 = 0.28782313662425572f;   // ln(10000)/32
    float freq = __expf(-(float)i * LOG1E4_OVER32);
    float ang  = (float)s * freq;
    float c, sn;
    __sincosf(ang, &sn, &c);
    size_t base = (size_t)s * DMODEL + hh * DKH + 2 * i;
    float e = b2f(q[base]), o_ = b2f(q[base + 1]);
    q[base]     = f2b(e * c - o_ * sn);
    q[base + 1] = f2b(e * sn + o_ * c);
    e = b2f(k[base]); o_ = b2f(k[base + 1]);
    k[base]     = f2b(e * c - o_ * sn);
    k[base + 1] = f2b(e * sn + o_ * c);
}

// ---------------------------------------------------------------------------
// Causal flash attention, bf16 in/out, MFMA 16x16x32, fp32 accumulate.
// Round-9 changes vs the passing round-8 kernel:
//  * LPT remap: qi = gridDim.x-1-blockIdx.x (longest blocks dispatch first).
//  * Async staging: next tile's K/V prefetched into registers during compute;
//    only reg->LDS writes sit between the two barriers.
//  * V^T stored XOR-swizzled: Vs[d][key ^ ((d>>3)<<3)] -> per-store banks all
//    distinct (was 16-way conflicted); PV read applies the same XOR (keeps
//    8-contiguity and 16B alignment since XOR touches only key bits 3..5).
//  * Softmax reductions via DPP row_ror (VALU) instead of 8 serial DS-shfls.
// ---------------------------------------------------------------------------
#define LSTR 72

__global__ __launch_bounds__(256)
void attn_mfma(const ushort* __restrict__ Q, const ushort* __restrict__ K,
               const ushort* __restrict__ V, ushort* __restrict__ O) {
    __shared__ __attribute__((aligned(16))) ushort Ks[64 * LSTR];
    __shared__ __attribute__((aligned(16))) ushort Vs[64 * LSTR];   // [d][key^swz]
    __shared__ __attribute__((aligned(16))) ushort Ps[4][16 * LSTR];

    const int tid  = threadIdx.x;
    const int w    = tid >> 6;
    const int lane = tid & 63;
    const int lrow = lane & 15;
    const int lgrp = lane >> 4;
    const int h    = blockIdx.y;
    const int qi   = (int)gridDim.x - 1 - (int)blockIdx.x;   // LPT: big blocks first
    const int qbase = qi * 64;

    // ---- Q fragments: direct bf16 16B loads ----
    const int qr = qbase + w * 16 + lrow;
    const ushort* qp = Q + (size_t)qr * DMODEL + h * DKH + lgrp * 8;
    bf16x8 qfrag[2];
    qfrag[0] = *(const bf16x8*)(qp);
    qfrag[1] = *(const bf16x8*)(qp + 32);

    f32x4 o_acc[4];
#pragma unroll
    for (int t = 0; t < 4; t++) o_acc[t] = (f32x4){0.f, 0.f, 0.f, 0.f};
    float m_r[4], l_r[4];
#pragma unroll
    for (int r = 0; r < 4; r++) { m_r[r] = -INFINITY; l_r[r] = 0.f; }

    // staging geometry: chunk c = tid + cc*256; row (key) = c>>3, col (d) = (c&7)*8
    const int row0 = tid >> 3;          // 0..31
    const int col0 = (tid & 7) * 8;     // 0..56
    const ushort* Kp = K + (size_t)h * DKH;
    const ushort* Vp = V + (size_t)h * DKH;

    const int ktmax = qi;
    bf16x8 rk[2], rv[2];
    // prefetch tile 0
#pragma unroll
    for (int cc = 0; cc < 2; cc++) {
        const int row = row0 + cc * 32;
        rk[cc] = *(const bf16x8*)(Kp + (size_t)row * DMODEL + col0);
        rv[cc] = *(const bf16x8*)(Vp + (size_t)row * DMODEL + col0);
    }

    for (int kt = 0; kt <= ktmax; kt++) {
        const int kbase = kt * 64;
        __syncthreads();   // previous tile's compute done before overwrite
        // ---- write staged registers to LDS ----
#pragma unroll
        for (int cc = 0; cc < 2; cc++) {
            const int row = row0 + cc * 32;
            *(bf16x8*)&Ks[row * LSTR + col0] = rk[cc];
            const int vrow = row ^ (col0 & 56);   // XOR-swizzle: (d>>3)<<3 == col0&56
#pragma unroll
            for (int jj = 0; jj < 8; jj++)
                Vs[(col0 + jj) * LSTR + vrow] = (ushort)rv[cc][jj];
        }
        __syncthreads();

        // ---- prefetch next tile (latency hides under compute below) ----
        if (kt < ktmax) {
            const size_t nb = (size_t)(kbase + 64) * DMODEL;
#pragma unroll
            for (int cc = 0; cc < 2; cc++) {
                const int row = row0 + cc * 32;
                rk[cc] = *(const bf16x8*)(Kp + nb + (size_t)row * DMODEL + col0);
                rv[cc] = *(const bf16x8*)(Vp + nb + (size_t)row * DMODEL + col0);
            }
        }

        // ---- QK^T: S[16 q][64 keys] per wave ----
        f32x4 s[4];
#pragma unroll
        for (int n = 0; n < 4; n++) {
            f32x4 acc = (f32x4){0.f, 0.f, 0.f, 0.f};
#pragma unroll
            for (int ks = 0; ks < 2; ks++) {
                bf16x8 kf = *(const bf16x8*)&Ks[(n * 16 + lrow) * LSTR + lgrp * 8 + ks * 32];
                acc = __builtin_amdgcn_mfma_f32_16x16x32_bf16(qfrag[ks], kf, acc, 0, 0, 0);
            }
            s[n] = acc;
        }

        // ---- scale by 1/sqrt(64) + causal mask ----
        const int myq = qbase + w * 16 + lgrp * 4;
#pragma unroll
        for (int n = 0; n < 4; n++) {
            const int key = kbase + n * 16 + lrow;
#pragma unroll
            for (int r = 0; r < 4; r++)
                s[n][r] = (key > myq + r) ? -INFINITY : s[n][r] * 0.125f;
        }

        // ---- online softmax; row-reduce via DPP (16-lane rows) ----
        float alpha[4];
#pragma unroll
        for (int r = 0; r < 4; r++) {
            float t0 = fmaxf(fmaxf(s[0][r], s[1][r]), fmaxf(s[2][r], s[3][r]));
            float mnew = fmaxf(m_r[r], rowmax16(t0));
            alpha[r] = __expf(m_r[r] - mnew);   // exp(-inf)=0 on first tile
            m_r[r] = mnew;
        }
#pragma unroll
        for (int t = 0; t < 4; t++)
#pragma unroll
            for (int r = 0; r < 4; r++) o_acc[t][r] *= alpha[r];

        float psum[4] = {0.f, 0.f, 0.f, 0.f};
#pragma unroll
        for (int n = 0; n < 4; n++) {
#pragma unroll
            for (int r = 0; r < 4; r++) {
                float p = __expf(s[n][r] - m_r[r]);   // masked: exp(-inf)=0
                psum[r] += p;
                Ps[w][(lgrp * 4 + r) * LSTR + n * 16 + lrow] = f2b(p);
            }
        }
#pragma unroll
        for (int r = 0; r < 4; r++)
            l_r[r] = l_r[r] * alpha[r] + rowsum16(psum[r]);

        // ---- PV: O += P * V   (P from wave-private LDS, V^T swizzled) ----
#pragma unroll
        for (int ks = 0; ks < 2; ks++) {
            bf16x8 pa = *(const bf16x8*)&Ps[w][lrow * LSTR + lgrp * 8 + ks * 32];
#pragma unroll
            for (int t = 0; t < 4; t++) {
                const int xr = (2 * t + (lrow >> 3)) << 3;   // (d>>3)<<3, d = t*16+lrow
                bf16x8 vb = *(const bf16x8*)&Vs[(t * 16 + lrow) * LSTR + ((lgrp * 8 + ks * 32) ^ xr)];
                o_acc[t] = __builtin_amdgcn_mfma_f32_16x16x32_bf16(pa, vb, o_acc[t], 0, 0, 0);
            }
        }
    }

    // ---- epilogue: normalize and store bf16 ----
    float invl[4];
#pragma unroll
    for (int r = 0; r < 4; r++) invl[r] = 1.0f / l_r[r];
    ushort* op = O + (size_t)(qbase + w * 16) * DMODEL + h * DKH;
#pragma unroll
    for (int t = 0; t < 4; t++)
#pragma unroll
        for (int r = 0; r < 4; r++)
            op[(size_t)(lgrp * 4 + r) * DMODEL + t * 16 + lrow] = f2b(o_acc[t][r] * invl[r]);
}

// ---------------------------------------------------------------------------
extern "C" void kernel_launch(void* const* d_in, const int* in_sizes, int n_in,
                              void* d_out, int out_size, void* d_ws, size_t ws_size,
                              hipStream_t stream) {
    const float* x  = (const float*)d_in[0];
    const float* Wq = (const float*)d_in[1];
    const float* Wk = (const float*)d_in[2];
    const float* Wv = (const float*)d_in[3];
    const float* Wo = (const float*)d_in[4];
    float* out = (float*)d_out;

    const size_t NM = (size_t)SEQ * DMODEL;      // 4 M elems
    const size_t NW = (size_t)DMODEL * DMODEL;   // 1 M elems
    ushort* qb  = (ushort*)d_ws;
    ushort* kb  = qb + NM;
    ushort* vb  = kb + NM;
    ushort* ob  = vb + NM;
    ushort* xb  = ob + NM;
    ushort* wqb = xb + NM;
    ushort* wkb = wqb + NW;
    ushort* wvb = wkb + NW;
    ushort* wob = wvb + NW;   // total 48 MB

    conv_bf16<<<8192, 256, 0, stream>>>(x, Wq, Wk, Wv, Wo, xb, wqb, wkb, wvb, wob);

    dim3 ggrid(DMODEL / 128, SEQ / 128);   // (8, 32)
    gemm_bf16<true><<<ggrid, 256, 0, stream>>>(xb, wqb, qb, SEQ, DMODEL, DMODEL);
    gemm_bf16<true><<<ggrid, 256, 0, stream>>>(xb, wkb, kb, SEQ, DMODEL, DMODEL);
    gemm_bf16<true><<<ggrid, 256, 0, stream>>>(xb, wvb, vb, SEQ, DMODEL, DMODEL);

    rope_bf16<<<SEQ * (DMODEL / 2) / 256, 256, 0, stream>>>(qb, kb);

    attn_mfma<<<dim3(SEQ / 64, NHEAD), 256, 0, stream>>>(qb, kb, vb, ob);

    gemm_bf16<false><<<ggrid, 256, 0, stream>>>(ob, wob, out, SEQ, DMODEL, DMODEL);
}